// Round 1
// baseline (1600.546 us; speedup 1.0000x reference)
//
#include <hip/hip_runtime.h>

// NuclideGNN: 3-layer GCN on MI355X.
// Pipeline: degree hist -> scan (CSR offsets + dinv) -> scatter (CSR col idx)
//           -> input proj -> [GEMM -> fused gather+BN+ReLU+residual] x3
// No float atomics: aggregation is a CSR gather, one block per dst node.

#define NN 100000
#define NE 3200000
#define FI 7
#define HD 128
#define DD 64
#define EPS 1e-5f

// ---------------- CSR build ----------------

__global__ __launch_bounds__(256) void hist_kernel(const int* __restrict__ ei,
                                                   int* __restrict__ cnt) {
    int e = blockIdx.x * 256 + threadIdx.x;
    if (e < NE) atomicAdd(&cnt[ei[NE + e]], 1);  // dst row of edge_index
}

__global__ __launch_bounds__(1024) void scan_kernel(const int* __restrict__ cnt,
                                                    int* __restrict__ rowstart,
                                                    int* __restrict__ cursor,
                                                    float* __restrict__ dinv) {
    __shared__ int tsum[1024];
    const int tid = threadIdx.x;
    const int CH = (NN + 1023) / 1024;  // 98 elements per thread
    const int lo = tid * CH;
    const int hi = min(lo + CH, NN);
    int s = 0;
    for (int i = lo; i < hi; ++i) s += cnt[i];
    tsum[tid] = s;
    __syncthreads();
    // Hillis-Steele inclusive scan over 1024 thread sums
    for (int off = 1; off < 1024; off <<= 1) {
        int v = (tid >= off) ? tsum[tid - off] : 0;
        __syncthreads();
        tsum[tid] += v;
        __syncthreads();
    }
    int run = (tid == 0) ? 0 : tsum[tid - 1];  // exclusive prefix of my chunk
    for (int i = lo; i < hi; ++i) {
        int c = cnt[i];
        rowstart[i] = run;
        cursor[i] = run;
        dinv[i] = rsqrtf((float)c + 1.0f);  // deg includes self-loop
        run += c;
    }
    if (tid == 0) rowstart[NN] = NE;
}

__global__ __launch_bounds__(256) void scatter_kernel(const int* __restrict__ ei,
                                                      int* __restrict__ cursor,
                                                      int* __restrict__ esrc) {
    int e = blockIdx.x * 256 + threadIdx.x;
    if (e < NE) {
        int s = ei[e];       // src
        int d = ei[NE + e];  // dst
        int p = atomicAdd(&cursor[d], 1);
        esrc[p] = s;
    }
}

// ---------------- input projection: h = relu(x @ W_in + b_in) ----------------

__global__ __launch_bounds__(256) void inproj_kernel(const float* __restrict__ x,
                                                     const float* __restrict__ W_in,
                                                     const float* __restrict__ b_in,
                                                     float* __restrict__ hA) {
    int n = blockIdx.x * 2 + (threadIdx.x >> 7);
    int j = threadIdx.x & 127;
    float acc = b_in[j];
#pragma unroll
    for (int f = 0; f < FI; ++f) acc += x[n * FI + f] * W_in[f * HD + j];
    hA[n * HD + j] = fmaxf(acc, 0.f);
}

// ---------------- GEMM: B[N,DO] = A[N,128] @ W[128,DO] ----------------
// 16 nodes x DO cols per 256-thread block; each thread holds 16*DO/256 rows.

template <int DO>
__global__ __launch_bounds__(256) void gemm_kernel(const float* __restrict__ A,
                                                   const float* __restrict__ W,
                                                   float* __restrict__ B) {
    constexpr int NPB = 16;
    constexpr int GROUPS = 256 / DO;   // 2 (DO=128) or 4 (DO=64)
    constexpr int NPT = NPB / GROUPS;  // 8 or 4
    __shared__ float sh[NPB][HD];
    const int tid = threadIdx.x;
    const int n0 = blockIdx.x * NPB;
    for (int i = tid; i < NPB * HD; i += 256)
        sh[i / HD][i % HD] = A[(size_t)(n0 + i / HD) * HD + (i % HD)];
    __syncthreads();
    const int col = tid % DO;
    const int grp = tid / DO;
    float acc[NPT];
#pragma unroll
    for (int i = 0; i < NPT; ++i) acc[i] = 0.f;
    for (int k = 0; k < HD; ++k) {
        float w = W[k * DO + col];
#pragma unroll
        for (int i = 0; i < NPT; ++i) acc[i] += sh[grp * NPT + i][k] * w;
    }
#pragma unroll
    for (int i = 0; i < NPT; ++i)
        B[(size_t)(n0 + grp * NPT + i) * DO + col] = acc[i];
}

// ---------------- fused gather + self-loop + bias + BN (+ ReLU + residual) ----
// One block per dst node, DO threads (1 col each). acc = dinv[n]*XW[n] (self)
//   + sum_e dinv[src]*XW[src]; then *dinv[n], +b, BN, optional relu+residual.

template <int DO, bool RELU_RES>
__global__ __launch_bounds__(DO) void gather_kernel(const float* __restrict__ hXW,
                                                    float* __restrict__ resOut,
                                                    const int* __restrict__ rowstart,
                                                    const int* __restrict__ esrc,
                                                    const float* __restrict__ dinv,
                                                    const float* __restrict__ bias,
                                                    const float* __restrict__ g,
                                                    const float* __restrict__ be,
                                                    const float* __restrict__ m,
                                                    const float* __restrict__ v) {
    __shared__ int s_idx[64];
    __shared__ float s_dv[64];
    const int n = blockIdx.x;
    const int col = threadIdx.x;
    const int rs = rowstart[n];
    const int re = rowstart[n + 1];
    const float dn = dinv[n];
    float acc0 = hXW[(size_t)n * DO + col] * dn;  // self-loop term
    float acc1 = 0.f;
    for (int base = rs; base < re; base += 64) {
        const int c = min(64, re - base);
        __syncthreads();
        if (threadIdx.x < c) {
            int s = esrc[base + threadIdx.x];
            s_idx[threadIdx.x] = s;
            s_dv[threadIdx.x] = dinv[s];
        }
        __syncthreads();
        int j = 0;
        for (; j + 1 < c; j += 2) {
            acc0 += hXW[(size_t)s_idx[j] * DO + col] * s_dv[j];
            acc1 += hXW[(size_t)s_idx[j + 1] * DO + col] * s_dv[j + 1];
        }
        if (j < c) acc0 += hXW[(size_t)s_idx[j] * DO + col] * s_dv[j];
    }
    float val = (acc0 + acc1) * dn + bias[col];
    const float sc = g[col] * rsqrtf(v[col] + EPS);
    val = (val - m[col]) * sc + be[col];
    if (RELU_RES) {
        resOut[(size_t)n * DO + col] = fmaxf(val, 0.f) + resOut[(size_t)n * DO + col];
    } else {
        resOut[(size_t)n * DO + col] = val;
    }
}

// ---------------- launch ----------------

extern "C" void kernel_launch(void* const* d_in, const int* in_sizes, int n_in,
                              void* d_out, int out_size, void* d_ws, size_t ws_size,
                              hipStream_t stream) {
    const float* x    = (const float*)d_in[0];
    const int*   ei   = (const int*)d_in[1];
    const float* W_in = (const float*)d_in[2];
    const float* b_in = (const float*)d_in[3];
    const float* Wl[3] = {(const float*)d_in[4], (const float*)d_in[10], (const float*)d_in[16]};
    const float* bl[3] = {(const float*)d_in[5], (const float*)d_in[11], (const float*)d_in[17]};
    const float* gl[3] = {(const float*)d_in[6], (const float*)d_in[12], (const float*)d_in[18]};
    const float* bel[3] = {(const float*)d_in[7], (const float*)d_in[13], (const float*)d_in[19]};
    const float* ml[3] = {(const float*)d_in[8], (const float*)d_in[14], (const float*)d_in[20]};
    const float* vl[3] = {(const float*)d_in[9], (const float*)d_in[15], (const float*)d_in[21]};
    float* out = (float*)d_out;

    char* ws = (char*)d_ws;
    size_t off = 0;
    auto carve = [&](size_t bytes) {
        void* p = ws + off;
        off += (bytes + 255) & ~(size_t)255;
        return p;
    };
    int*   cnt      = (int*)carve((NN + 1) * sizeof(int));
    int*   rowstart = (int*)carve((NN + 1) * sizeof(int));
    int*   cursor   = (int*)carve(NN * sizeof(int));
    float* dinv     = (float*)carve(NN * sizeof(float));
    int*   esrc     = (int*)carve((size_t)NE * sizeof(int));
    float* hA       = (float*)carve((size_t)NN * HD * sizeof(float));
    float* hB       = (float*)carve((size_t)NN * HD * sizeof(float));
    (void)ws_size;

    hipMemsetAsync(cnt, 0, (NN + 1) * sizeof(int), stream);

    const int EB = (NE + 255) / 256;  // 12500
    hist_kernel<<<EB, 256, 0, stream>>>(ei, cnt);
    scan_kernel<<<1, 1024, 0, stream>>>(cnt, rowstart, cursor, dinv);
    scatter_kernel<<<EB, 256, 0, stream>>>(ei, cursor, esrc);

    inproj_kernel<<<NN / 2, 256, 0, stream>>>(x, W_in, b_in, hA);

    // layer 0
    gemm_kernel<128><<<NN / 16, 256, 0, stream>>>(hA, Wl[0], hB);
    gather_kernel<128, true><<<NN, 128, 0, stream>>>(hB, hA, rowstart, esrc, dinv,
                                                     bl[0], gl[0], bel[0], ml[0], vl[0]);
    // layer 1
    gemm_kernel<128><<<NN / 16, 256, 0, stream>>>(hA, Wl[1], hB);
    gather_kernel<128, true><<<NN, 128, 0, stream>>>(hB, hA, rowstart, esrc, dinv,
                                                     bl[1], gl[1], bel[1], ml[1], vl[1]);
    // layer 2 (BN only, write d_out)
    gemm_kernel<64><<<NN / 16, 256, 0, stream>>>(hA, Wl[2], hB);
    gather_kernel<64, false><<<NN, 64, 0, stream>>>(hB, out, rowstart, esrc, dinv,
                                                    bl[2], gl[2], bel[2], ml[2], vl[2]);
}

// Round 3
// 1284.204 us; speedup vs baseline: 1.2463x; 1.2463x over previous
//
#include <hip/hip_runtime.h>

// NuclideGNN: 3-layer GCN on MI355X.
// R2: fix layer-2 gather launch config (kernel assumes 128 thr/block; was
//     launched with 64 -> read uninitialized LDS edge indices).
// Pipeline: hist -> scan(a,b,c) -> scatter -> inproj -> [gemm -> gather]x3

#define NN 100000
#define NE 3200000
#define FI 7
#define HD 128
#define DD 64
#define EPS 1e-5f
#define SCB 256
#define NSCB ((NN + SCB - 1) / SCB)  // 391

// ---------------- CSR build ----------------

__global__ __launch_bounds__(256) void hist_kernel(const int* __restrict__ ei,
                                                   int* __restrict__ cnt) {
    int e = blockIdx.x * 256 + threadIdx.x;
    if (e < NE) atomicAdd(&cnt[ei[NE + e]], 1);  // dst row of edge_index
}

__global__ __launch_bounds__(SCB) void scan_a(const int* __restrict__ cnt,
                                              int* __restrict__ bsum) {
    __shared__ int red[SCB];
    int i = blockIdx.x * SCB + threadIdx.x;
    red[threadIdx.x] = (i < NN) ? cnt[i] : 0;
    __syncthreads();
    for (int s = SCB / 2; s > 0; s >>= 1) {
        if (threadIdx.x < s) red[threadIdx.x] += red[threadIdx.x + s];
        __syncthreads();
    }
    if (threadIdx.x == 0) bsum[blockIdx.x] = red[0];
}

__global__ __launch_bounds__(512) void scan_b(const int* __restrict__ bsum,
                                              int* __restrict__ bpre) {
    __shared__ int sh[512];
    int t = threadIdx.x;
    sh[t] = (t < NSCB) ? bsum[t] : 0;
    __syncthreads();
    for (int off = 1; off < 512; off <<= 1) {
        int v = (t >= off) ? sh[t - off] : 0;
        __syncthreads();
        sh[t] += v;
        __syncthreads();
    }
    if (t < NSCB) bpre[t] = (t == 0) ? 0 : sh[t - 1];
}

__global__ __launch_bounds__(SCB) void scan_c(const int* __restrict__ cnt,
                                              const int* __restrict__ bpre,
                                              int* __restrict__ rowstart,
                                              int* __restrict__ cursor,
                                              float* __restrict__ dinv) {
    __shared__ int sh[SCB];
    const int t = threadIdx.x;
    const int i = blockIdx.x * SCB + t;
    const int c = (i < NN) ? cnt[i] : 0;
    sh[t] = c;
    __syncthreads();
    for (int off = 1; off < SCB; off <<= 1) {
        int v = (t >= off) ? sh[t - off] : 0;
        __syncthreads();
        sh[t] += v;
        __syncthreads();
    }
    if (i < NN) {
        int excl = bpre[blockIdx.x] + sh[t] - c;
        rowstart[i] = excl;
        cursor[i] = excl;
        dinv[i] = rsqrtf((float)c + 1.0f);  // deg includes self-loop
    }
    if (i == 0) rowstart[NN] = NE;
}

__global__ __launch_bounds__(256) void scatter_kernel(const int* __restrict__ ei,
                                                      int* __restrict__ cursor,
                                                      int* __restrict__ esrc) {
    int e = blockIdx.x * 256 + threadIdx.x;
    if (e < NE) {
        int s = ei[e];       // src
        int d = ei[NE + e];  // dst
        int p = atomicAdd(&cursor[d], 1);
        esrc[p] = s;
    }
}

// ---------------- input projection: h = relu(x @ W_in + b_in) ----------------

__global__ __launch_bounds__(256) void inproj_kernel(const float* __restrict__ x,
                                                     const float* __restrict__ W_in,
                                                     const float* __restrict__ b_in,
                                                     float* __restrict__ hA) {
    int n = blockIdx.x * 2 + (threadIdx.x >> 7);
    int j = threadIdx.x & 127;
    float acc = b_in[j];
#pragma unroll
    for (int f = 0; f < FI; ++f) acc += x[n * FI + f] * W_in[f * HD + j];
    hA[n * HD + j] = fmaxf(acc, 0.f);
}

// ---------------- GEMM: B[N,DO] = A[N,128] @ W[128,DO] ----------------
// 16 nodes x DO cols per 256-thread block; k unrolled by 4, ds_read_b128.

template <int DO>
__global__ __launch_bounds__(256) void gemm_kernel(const float* __restrict__ A,
                                                   const float* __restrict__ W,
                                                   float* __restrict__ B) {
    constexpr int NPB = 16;
    constexpr int GROUPS = 256 / DO;   // 2 (DO=128) or 4 (DO=64)
    constexpr int NPT = NPB / GROUPS;  // 8 or 4
    __shared__ float sh[NPB][HD];
    const int tid = threadIdx.x;
    const int n0 = blockIdx.x * NPB;
    // float4 tile load: 16*128/4 = 512 float4s, 2 per thread
    for (int i = tid; i < NPB * HD / 4; i += 256) {
        int r = i >> 5, kq = i & 31;
        ((float4*)&sh[r][0])[kq] = ((const float4*)(A + (size_t)(n0 + r) * HD))[kq];
    }
    __syncthreads();
    const int col = tid % DO;
    const int grp = tid / DO;
    float acc[NPT];
#pragma unroll
    for (int i = 0; i < NPT; ++i) acc[i] = 0.f;
    for (int k4 = 0; k4 < HD / 4; ++k4) {
        const float w0 = W[(k4 * 4 + 0) * DO + col];
        const float w1 = W[(k4 * 4 + 1) * DO + col];
        const float w2 = W[(k4 * 4 + 2) * DO + col];
        const float w3 = W[(k4 * 4 + 3) * DO + col];
#pragma unroll
        for (int i = 0; i < NPT; ++i) {
            const float4 a = *(const float4*)&sh[grp * NPT + i][k4 * 4];
            acc[i] += a.x * w0 + a.y * w1 + a.z * w2 + a.w * w3;
        }
    }
#pragma unroll
    for (int i = 0; i < NPT; ++i)
        B[(size_t)(n0 + grp * NPT + i) * DO + col] = acc[i];
}

// ---------- fused gather + self-loop + bias + BN (+ ReLU + residual) ----------
// One block (128 thr) per dst node. thread t: col-quad q=t&(QN-1), edge-group
// grp=t>>log2(QN). float4 loads, 2 accumulator chains, LDS cross-group reduce.
// MUST be launched with 128 threads (edge tile size == 128).

template <int DO, bool RELU_RES>
__global__ __launch_bounds__(128) void gather_kernel(const float* __restrict__ hXW,
                                                     float* __restrict__ resOut,
                                                     const int* __restrict__ rowstart,
                                                     const int* __restrict__ esrc,
                                                     const float* __restrict__ dinv,
                                                     const float* __restrict__ bias,
                                                     const float* __restrict__ g,
                                                     const float* __restrict__ be,
                                                     const float* __restrict__ m,
                                                     const float* __restrict__ v) {
    constexpr int QN = DO / 4;        // 32 (DO=128) or 16 (DO=64) col-quads
    constexpr int NG = 128 / QN;      // 4 or 8 edge groups
    __shared__ int s_idx[128];
    __shared__ float s_dv[128];
    __shared__ float4 s_red[128];
    const int n = blockIdx.x;
    const int t = threadIdx.x;
    const int rs = rowstart[n];
    const int re = rowstart[n + 1];
    const float dn = dinv[n];
    const int q = t & (QN - 1);
    const int grp = t / QN;
    float4 acc0 = {0.f, 0.f, 0.f, 0.f};
    float4 acc1 = {0.f, 0.f, 0.f, 0.f};
    for (int base = rs; base < re; base += 128) {
        const int c = min(128, re - base);
        __syncthreads();
        if (t < c) {
            int s = esrc[base + t];
            s_idx[t] = s;
            s_dv[t] = dinv[s];
        }
        __syncthreads();
        for (int j = grp; j < c; j += 2 * NG) {
            {
                const float4 hv = *(const float4*)(hXW + (size_t)s_idx[j] * DO + q * 4);
                const float w = s_dv[j];
                acc0.x += hv.x * w; acc0.y += hv.y * w;
                acc0.z += hv.z * w; acc0.w += hv.w * w;
            }
            if (j + NG < c) {
                const float4 hv = *(const float4*)(hXW + (size_t)s_idx[j + NG] * DO + q * 4);
                const float w = s_dv[j + NG];
                acc1.x += hv.x * w; acc1.y += hv.y * w;
                acc1.z += hv.z * w; acc1.w += hv.w * w;
            }
        }
    }
    acc0.x += acc1.x; acc0.y += acc1.y; acc0.z += acc1.z; acc0.w += acc1.w;
    s_red[t] = acc0;
    __syncthreads();
    if (t < QN) {
        float4 sum = s_red[t];
#pragma unroll
        for (int k = 1; k < NG; ++k) {
            const float4 a = s_red[t + k * QN];
            sum.x += a.x; sum.y += a.y; sum.z += a.z; sum.w += a.w;
        }
        const float4 self = *(const float4*)(hXW + (size_t)n * DO + t * 4);
        const float4 b4 = *(const float4*)(bias + t * 4);
        const float4 g4 = *(const float4*)(g + t * 4);
        const float4 be4 = *(const float4*)(be + t * 4);
        const float4 m4 = *(const float4*)(m + t * 4);
        const float4 v4 = *(const float4*)(v + t * 4);
        float4 val;
        val.x = (sum.x + dn * self.x) * dn + b4.x;
        val.y = (sum.y + dn * self.y) * dn + b4.y;
        val.z = (sum.z + dn * self.z) * dn + b4.z;
        val.w = (sum.w + dn * self.w) * dn + b4.w;
        val.x = (val.x - m4.x) * (g4.x * rsqrtf(v4.x + EPS)) + be4.x;
        val.y = (val.y - m4.y) * (g4.y * rsqrtf(v4.y + EPS)) + be4.y;
        val.z = (val.z - m4.z) * (g4.z * rsqrtf(v4.z + EPS)) + be4.z;
        val.w = (val.w - m4.w) * (g4.w * rsqrtf(v4.w + EPS)) + be4.w;
        float4* outp = (float4*)(resOut + (size_t)n * DO + t * 4);
        if (RELU_RES) {
            const float4 r = *outp;
            val.x = fmaxf(val.x, 0.f) + r.x;
            val.y = fmaxf(val.y, 0.f) + r.y;
            val.z = fmaxf(val.z, 0.f) + r.z;
            val.w = fmaxf(val.w, 0.f) + r.w;
        }
        *outp = val;
    }
}

// ---------------- launch ----------------

extern "C" void kernel_launch(void* const* d_in, const int* in_sizes, int n_in,
                              void* d_out, int out_size, void* d_ws, size_t ws_size,
                              hipStream_t stream) {
    const float* x    = (const float*)d_in[0];
    const int*   ei   = (const int*)d_in[1];
    const float* W_in = (const float*)d_in[2];
    const float* b_in = (const float*)d_in[3];
    const float* Wl[3] = {(const float*)d_in[4], (const float*)d_in[10], (const float*)d_in[16]};
    const float* bl[3] = {(const float*)d_in[5], (const float*)d_in[11], (const float*)d_in[17]};
    const float* gl[3] = {(const float*)d_in[6], (const float*)d_in[12], (const float*)d_in[18]};
    const float* bel[3] = {(const float*)d_in[7], (const float*)d_in[13], (const float*)d_in[19]};
    const float* ml[3] = {(const float*)d_in[8], (const float*)d_in[14], (const float*)d_in[20]};
    const float* vl[3] = {(const float*)d_in[9], (const float*)d_in[15], (const float*)d_in[21]};
    float* out = (float*)d_out;

    char* ws = (char*)d_ws;
    size_t off = 0;
    auto carve = [&](size_t bytes) {
        void* p = ws + off;
        off += (bytes + 255) & ~(size_t)255;
        return p;
    };
    int*   cnt      = (int*)carve((NN + 1) * sizeof(int));
    int*   rowstart = (int*)carve((NN + 1) * sizeof(int));
    int*   cursor   = (int*)carve(NN * sizeof(int));
    float* dinv     = (float*)carve(NN * sizeof(float));
    int*   bsum     = (int*)carve(512 * sizeof(int));
    int*   bpre     = (int*)carve(512 * sizeof(int));
    int*   esrc     = (int*)carve((size_t)NE * sizeof(int));
    float* hA       = (float*)carve((size_t)NN * HD * sizeof(float));
    float* hB       = (float*)carve((size_t)NN * HD * sizeof(float));
    (void)ws_size;

    hipMemsetAsync(cnt, 0, (NN + 1) * sizeof(int), stream);

    const int EB = (NE + 255) / 256;  // 12500
    hist_kernel<<<EB, 256, 0, stream>>>(ei, cnt);
    scan_a<<<NSCB, SCB, 0, stream>>>(cnt, bsum);
    scan_b<<<1, 512, 0, stream>>>(bsum, bpre);
    scan_c<<<NSCB, SCB, 0, stream>>>(cnt, bpre, rowstart, cursor, dinv);
    scatter_kernel<<<EB, 256, 0, stream>>>(ei, cursor, esrc);

    inproj_kernel<<<NN / 2, 256, 0, stream>>>(x, W_in, b_in, hA);

    // layer 0
    gemm_kernel<128><<<NN / 16, 256, 0, stream>>>(hA, Wl[0], hB);
    gather_kernel<128, true><<<NN, 128, 0, stream>>>(hB, hA, rowstart, esrc, dinv,
                                                     bl[0], gl[0], bel[0], ml[0], vl[0]);
    // layer 1
    gemm_kernel<128><<<NN / 16, 256, 0, stream>>>(hA, Wl[1], hB);
    gather_kernel<128, true><<<NN, 128, 0, stream>>>(hB, hA, rowstart, esrc, dinv,
                                                     bl[1], gl[1], bel[1], ml[1], vl[1]);
    // layer 2 (BN only, write d_out) — gemm BEFORE gather; 128 threads (edge tile = 128)
    gemm_kernel<64><<<NN / 16, 256, 0, stream>>>(hA, Wl[2], hB);
    gather_kernel<64, false><<<NN, 128, 0, stream>>>(hB, out, rowstart, esrc, dinv,
                                                     bl[2], gl[2], bel[2], ml[2], vl[2]);
}

// Round 4
// 997.235 us; speedup vs baseline: 1.6050x; 1.2878x over previous
//
#include <hip/hip_runtime.h>

// NuclideGNN: 3-layer GCN on MI355X.
// R3: replace hist+scan+scatter (random-4B-write bound, 194MB writeback for a
//     12.8MB buffer) with 2-level bucket sort: P1 block-hist+reserve ->
//     P2 bucket scan -> P3 binned placement (packed dst|src) -> P4 per-bucket
//     finalize (local hist/scan -> rowstart/dinv + windowed esrc scatter).
// Pipeline: P1 -> P2 -> P3 -> P4 -> inproj -> [gemm -> gather]x3

#define NN 100000
#define NE 3200000
#define FI 7
#define HD 128
#define DD 64
#define EPS 1e-5f
#define NB 196                        // buckets of 512 dst nodes (dst>>9)
#define EPB 8192                      // edges per P1/P3 block (256 thr x 32)
#define NBLK ((NE + EPB - 1) / EPB)   // 391

// ---------------- CSR build: two-level bucket sort ----------------

__global__ __launch_bounds__(256) void p1_bucket_hist(const int* __restrict__ ei,
                                                      int* __restrict__ bcnt,
                                                      int* __restrict__ blk_off) {
    __shared__ int h[NB];
    const int t = threadIdx.x;
    for (int b = t; b < NB; b += 256) h[b] = 0;
    __syncthreads();
    const int base = blockIdx.x * EPB;
#pragma unroll 4
    for (int i = 0; i < EPB / 256; ++i) {
        int e = base + i * 256 + t;
        if (e < NE) atomicAdd(&h[ei[NE + e] >> 9], 1);
    }
    __syncthreads();
    for (int b = t; b < NB; b += 256) {
        int c = h[b];
        blk_off[blockIdx.x * NB + b] = c ? atomicAdd(&bcnt[b], c) : 0;
    }
}

__global__ __launch_bounds__(256) void p2_bucket_scan(const int* __restrict__ bcnt,
                                                      int* __restrict__ bstart) {
    __shared__ int sh[256];
    const int t = threadIdx.x;
    const int myc = (t < NB) ? bcnt[t] : 0;
    sh[t] = myc;
    __syncthreads();
    for (int off = 1; off < 256; off <<= 1) {
        int v = (t >= off) ? sh[t - off] : 0;
        __syncthreads();
        sh[t] += v;
        __syncthreads();
    }
    if (t < NB) bstart[t] = sh[t] - myc;  // exclusive prefix
    if (t == 0) bstart[NB] = NE;
}

__global__ __launch_bounds__(256) void p3_bin(const int* __restrict__ ei,
                                              const int* __restrict__ bstart,
                                              const int* __restrict__ blk_off,
                                              int* __restrict__ ebin) {
    __shared__ int cur[NB];
    const int t = threadIdx.x;
    for (int b = t; b < NB; b += 256)
        cur[b] = bstart[b] + blk_off[blockIdx.x * NB + b];
    __syncthreads();
    const int base = blockIdx.x * EPB;
#pragma unroll 4
    for (int i = 0; i < EPB / 256; ++i) {
        int e = base + i * 256 + t;
        if (e < NE) {
            int s = ei[e];       // src (< 2^17)
            int d = ei[NE + e];  // dst
            int p = atomicAdd(&cur[d >> 9], 1);
            ebin[p] = ((d & 511) << 23) | s;  // pack local-dst | src
        }
    }
}

__global__ __launch_bounds__(512) void p4_finalize(const int* __restrict__ bstart,
                                                   const int* __restrict__ ebin,
                                                   int* __restrict__ esrc,
                                                   int* __restrict__ rowstart,
                                                   float* __restrict__ dinv) {
    __shared__ int lh[512];  // local degree
    __shared__ int sc[512];  // scan buffer
    __shared__ int lc[512];  // local cursor
    const int t = threadIdx.x;
    const int b = blockIdx.x;
    const int n0 = b << 9;
    const int ebase = bstart[b];
    const int ecnt = bstart[b + 1] - ebase;
    lh[t] = 0;
    __syncthreads();
    for (int i = t; i < ecnt; i += 512)
        atomicAdd(&lh[((unsigned)ebin[ebase + i]) >> 23], 1);
    __syncthreads();
    const int c = lh[t];
    sc[t] = c;
    __syncthreads();
    for (int off = 1; off < 512; off <<= 1) {
        int v = (t >= off) ? sc[t - off] : 0;
        __syncthreads();
        sc[t] += v;
        __syncthreads();
    }
    const int excl = ebase + sc[t] - c;  // global rowstart for node n0+t
    lc[t] = excl;
    const int node = n0 + t;
    if (node < NN) {
        rowstart[node] = excl;
        dinv[node] = rsqrtf((float)c + 1.0f);  // deg includes self-loop
    }
    if (b == NB - 1 && t == 0) rowstart[NN] = NE;
    __syncthreads();
    for (int i = t; i < ecnt; i += 512) {
        int v = ebin[ebase + i];
        int p = atomicAdd(&lc[((unsigned)v) >> 23], 1);
        esrc[p] = v & 0x7FFFFF;  // writes land in a 65KB L2-hot window
    }
}

// ---------------- input projection: h = relu(x @ W_in + b_in) ----------------

__global__ __launch_bounds__(256) void inproj_kernel(const float* __restrict__ x,
                                                     const float* __restrict__ W_in,
                                                     const float* __restrict__ b_in,
                                                     float* __restrict__ hA) {
    int n = blockIdx.x * 2 + (threadIdx.x >> 7);
    int j = threadIdx.x & 127;
    float acc = b_in[j];
#pragma unroll
    for (int f = 0; f < FI; ++f) acc += x[n * FI + f] * W_in[f * HD + j];
    hA[n * HD + j] = fmaxf(acc, 0.f);
}

// ---------------- GEMM: B[N,DO] = A[N,128] @ W[128,DO] ----------------
// 16 nodes x DO cols per 256-thread block; k unrolled by 4, ds_read_b128.

template <int DO>
__global__ __launch_bounds__(256) void gemm_kernel(const float* __restrict__ A,
                                                   const float* __restrict__ W,
                                                   float* __restrict__ B) {
    constexpr int NPB = 16;
    constexpr int GROUPS = 256 / DO;   // 2 (DO=128) or 4 (DO=64)
    constexpr int NPT = NPB / GROUPS;  // 8 or 4
    __shared__ float sh[NPB][HD];
    const int tid = threadIdx.x;
    const int n0 = blockIdx.x * NPB;
    for (int i = tid; i < NPB * HD / 4; i += 256) {
        int r = i >> 5, kq = i & 31;
        ((float4*)&sh[r][0])[kq] = ((const float4*)(A + (size_t)(n0 + r) * HD))[kq];
    }
    __syncthreads();
    const int col = tid % DO;
    const int grp = tid / DO;
    float acc[NPT];
#pragma unroll
    for (int i = 0; i < NPT; ++i) acc[i] = 0.f;
    for (int k4 = 0; k4 < HD / 4; ++k4) {
        const float w0 = W[(k4 * 4 + 0) * DO + col];
        const float w1 = W[(k4 * 4 + 1) * DO + col];
        const float w2 = W[(k4 * 4 + 2) * DO + col];
        const float w3 = W[(k4 * 4 + 3) * DO + col];
#pragma unroll
        for (int i = 0; i < NPT; ++i) {
            const float4 a = *(const float4*)&sh[grp * NPT + i][k4 * 4];
            acc[i] += a.x * w0 + a.y * w1 + a.z * w2 + a.w * w3;
        }
    }
#pragma unroll
    for (int i = 0; i < NPT; ++i)
        B[(size_t)(n0 + grp * NPT + i) * DO + col] = acc[i];
}

// ---------- fused gather + self-loop + bias + BN (+ ReLU + residual) ----------
// One block (128 thr) per dst node. thread t: col-quad q=t&(QN-1), edge-group
// grp=t>>log2(QN). float4 loads, 2 accumulator chains, LDS cross-group reduce.
// MUST be launched with 128 threads (edge tile size == 128).

template <int DO, bool RELU_RES>
__global__ __launch_bounds__(128) void gather_kernel(const float* __restrict__ hXW,
                                                     float* __restrict__ resOut,
                                                     const int* __restrict__ rowstart,
                                                     const int* __restrict__ esrc,
                                                     const float* __restrict__ dinv,
                                                     const float* __restrict__ bias,
                                                     const float* __restrict__ g,
                                                     const float* __restrict__ be,
                                                     const float* __restrict__ m,
                                                     const float* __restrict__ v) {
    constexpr int QN = DO / 4;        // 32 (DO=128) or 16 (DO=64) col-quads
    constexpr int NG = 128 / QN;      // 4 or 8 edge groups
    __shared__ int s_idx[128];
    __shared__ float s_dv[128];
    __shared__ float4 s_red[128];
    const int n = blockIdx.x;
    const int t = threadIdx.x;
    const int rs = rowstart[n];
    const int re = rowstart[n + 1];
    const float dn = dinv[n];
    const int q = t & (QN - 1);
    const int grp = t / QN;
    float4 acc0 = {0.f, 0.f, 0.f, 0.f};
    float4 acc1 = {0.f, 0.f, 0.f, 0.f};
    for (int base = rs; base < re; base += 128) {
        const int c = min(128, re - base);
        __syncthreads();
        if (t < c) {
            int s = esrc[base + t];
            s_idx[t] = s;
            s_dv[t] = dinv[s];
        }
        __syncthreads();
        for (int j = grp; j < c; j += 2 * NG) {
            {
                const float4 hv = *(const float4*)(hXW + (size_t)s_idx[j] * DO + q * 4);
                const float w = s_dv[j];
                acc0.x += hv.x * w; acc0.y += hv.y * w;
                acc0.z += hv.z * w; acc0.w += hv.w * w;
            }
            if (j + NG < c) {
                const float4 hv = *(const float4*)(hXW + (size_t)s_idx[j + NG] * DO + q * 4);
                const float w = s_dv[j + NG];
                acc1.x += hv.x * w; acc1.y += hv.y * w;
                acc1.z += hv.z * w; acc1.w += hv.w * w;
            }
        }
    }
    acc0.x += acc1.x; acc0.y += acc1.y; acc0.z += acc1.z; acc0.w += acc1.w;
    s_red[t] = acc0;
    __syncthreads();
    if (t < QN) {
        float4 sum = s_red[t];
#pragma unroll
        for (int k = 1; k < NG; ++k) {
            const float4 a = s_red[t + k * QN];
            sum.x += a.x; sum.y += a.y; sum.z += a.z; sum.w += a.w;
        }
        const float4 self = *(const float4*)(hXW + (size_t)n * DO + t * 4);
        const float4 b4 = *(const float4*)(bias + t * 4);
        const float4 g4 = *(const float4*)(g + t * 4);
        const float4 be4 = *(const float4*)(be + t * 4);
        const float4 m4 = *(const float4*)(m + t * 4);
        const float4 v4 = *(const float4*)(v + t * 4);
        float4 val;
        val.x = (sum.x + dn * self.x) * dn + b4.x;
        val.y = (sum.y + dn * self.y) * dn + b4.y;
        val.z = (sum.z + dn * self.z) * dn + b4.z;
        val.w = (sum.w + dn * self.w) * dn + b4.w;
        val.x = (val.x - m4.x) * (g4.x * rsqrtf(v4.x + EPS)) + be4.x;
        val.y = (val.y - m4.y) * (g4.y * rsqrtf(v4.y + EPS)) + be4.y;
        val.z = (val.z - m4.z) * (g4.z * rsqrtf(v4.z + EPS)) + be4.z;
        val.w = (val.w - m4.w) * (g4.w * rsqrtf(v4.w + EPS)) + be4.w;
        float4* outp = (float4*)(resOut + (size_t)n * DO + t * 4);
        if (RELU_RES) {
            const float4 r = *outp;
            val.x = fmaxf(val.x, 0.f) + r.x;
            val.y = fmaxf(val.y, 0.f) + r.y;
            val.z = fmaxf(val.z, 0.f) + r.z;
            val.w = fmaxf(val.w, 0.f) + r.w;
        }
        *outp = val;
    }
}

// ---------------- launch ----------------

extern "C" void kernel_launch(void* const* d_in, const int* in_sizes, int n_in,
                              void* d_out, int out_size, void* d_ws, size_t ws_size,
                              hipStream_t stream) {
    const float* x    = (const float*)d_in[0];
    const int*   ei   = (const int*)d_in[1];
    const float* W_in = (const float*)d_in[2];
    const float* b_in = (const float*)d_in[3];
    const float* Wl[3] = {(const float*)d_in[4], (const float*)d_in[10], (const float*)d_in[16]};
    const float* bl[3] = {(const float*)d_in[5], (const float*)d_in[11], (const float*)d_in[17]};
    const float* gl[3] = {(const float*)d_in[6], (const float*)d_in[12], (const float*)d_in[18]};
    const float* bel[3] = {(const float*)d_in[7], (const float*)d_in[13], (const float*)d_in[19]};
    const float* ml[3] = {(const float*)d_in[8], (const float*)d_in[14], (const float*)d_in[20]};
    const float* vl[3] = {(const float*)d_in[9], (const float*)d_in[15], (const float*)d_in[21]};
    float* out = (float*)d_out;

    char* ws = (char*)d_ws;
    size_t off = 0;
    auto carve = [&](size_t bytes) {
        void* p = ws + off;
        off += (bytes + 255) & ~(size_t)255;
        return p;
    };
    int*   bcnt     = (int*)carve(NB * sizeof(int));
    int*   bstart   = (int*)carve((NB + 1) * sizeof(int));
    int*   blk_off  = (int*)carve((size_t)NBLK * NB * sizeof(int));
    int*   rowstart = (int*)carve((NN + 1) * sizeof(int));
    float* dinv     = (float*)carve(NN * sizeof(float));
    int*   esrc     = (int*)carve((size_t)NE * sizeof(int));
    float* hA       = (float*)carve((size_t)NN * HD * sizeof(float));
    float* hB       = (float*)carve((size_t)NN * HD * sizeof(float));
    int*   ebin     = (int*)hB;  // alias: ebin dead before layer-0 GEMM writes hB
    (void)ws_size;

    hipMemsetAsync(bcnt, 0, NB * sizeof(int), stream);

    p1_bucket_hist<<<NBLK, 256, 0, stream>>>(ei, bcnt, blk_off);
    p2_bucket_scan<<<1, 256, 0, stream>>>(bcnt, bstart);
    p3_bin<<<NBLK, 256, 0, stream>>>(ei, bstart, blk_off, ebin);
    p4_finalize<<<NB, 512, 0, stream>>>(bstart, ebin, esrc, rowstart, dinv);

    inproj_kernel<<<NN / 2, 256, 0, stream>>>(x, W_in, b_in, hA);

    // layer 0
    gemm_kernel<128><<<NN / 16, 256, 0, stream>>>(hA, Wl[0], hB);
    gather_kernel<128, true><<<NN, 128, 0, stream>>>(hB, hA, rowstart, esrc, dinv,
                                                     bl[0], gl[0], bel[0], ml[0], vl[0]);
    // layer 1
    gemm_kernel<128><<<NN / 16, 256, 0, stream>>>(hA, Wl[1], hB);
    gather_kernel<128, true><<<NN, 128, 0, stream>>>(hB, hA, rowstart, esrc, dinv,
                                                     bl[1], gl[1], bel[1], ml[1], vl[1]);
    // layer 2 (BN only, write d_out); 128 threads (edge tile = 128)
    gemm_kernel<64><<<NN / 16, 256, 0, stream>>>(hA, Wl[2], hB);
    gather_kernel<64, false><<<NN, 128, 0, stream>>>(hB, out, rowstart, esrc, dinv,
                                                     bl[2], gl[2], bel[2], ml[2], vl[2]);
}

// Round 5
// 744.753 us; speedup vs baseline: 2.1491x; 1.3390x over previous
//
#include <hip/hip_runtime.h>

// NuclideGNN: 3-layer GCN on MI355X.
// R4: store GEMM product hB (XW) as bf16 -> halves gather fetch bytes
//     (833MB -> ~430MB per 128-wide gather; random-access BW floor scales
//     with bytes). fp32 accumulate in gather; residual stream stays fp32.
// Pipeline: P1 -> P2 -> P3 -> P4 -> inproj -> [gemm(bf16 out) -> gather]x3

#define NN 100000
#define NE 3200000
#define FI 7
#define HD 128
#define DD 64
#define EPS 1e-5f
#define NB 196                        // buckets of 512 dst nodes (dst>>9)
#define EPB 8192                      // edges per P1/P3 block (256 thr x 32)
#define NBLK ((NE + EPB - 1) / EPB)   // 391

__device__ __forceinline__ unsigned short f2bf(float f) {
    unsigned u = __float_as_uint(f);
    u += 0x7FFF + ((u >> 16) & 1);  // round-to-nearest-even
    return (unsigned short)(u >> 16);
}
__device__ __forceinline__ float bf2f(unsigned short s) {
    return __uint_as_float(((unsigned)s) << 16);
}

// ---------------- CSR build: two-level bucket sort ----------------

__global__ __launch_bounds__(256) void p1_bucket_hist(const int* __restrict__ ei,
                                                      int* __restrict__ bcnt,
                                                      int* __restrict__ blk_off) {
    __shared__ int h[NB];
    const int t = threadIdx.x;
    for (int b = t; b < NB; b += 256) h[b] = 0;
    __syncthreads();
    const int base = blockIdx.x * EPB;
#pragma unroll 4
    for (int i = 0; i < EPB / 256; ++i) {
        int e = base + i * 256 + t;
        if (e < NE) atomicAdd(&h[ei[NE + e] >> 9], 1);
    }
    __syncthreads();
    for (int b = t; b < NB; b += 256) {
        int c = h[b];
        blk_off[blockIdx.x * NB + b] = c ? atomicAdd(&bcnt[b], c) : 0;
    }
}

__global__ __launch_bounds__(256) void p2_bucket_scan(const int* __restrict__ bcnt,
                                                      int* __restrict__ bstart) {
    __shared__ int sh[256];
    const int t = threadIdx.x;
    const int myc = (t < NB) ? bcnt[t] : 0;
    sh[t] = myc;
    __syncthreads();
    for (int off = 1; off < 256; off <<= 1) {
        int v = (t >= off) ? sh[t - off] : 0;
        __syncthreads();
        sh[t] += v;
        __syncthreads();
    }
    if (t < NB) bstart[t] = sh[t] - myc;  // exclusive prefix
    if (t == 0) bstart[NB] = NE;
}

__global__ __launch_bounds__(256) void p3_bin(const int* __restrict__ ei,
                                              const int* __restrict__ bstart,
                                              const int* __restrict__ blk_off,
                                              int* __restrict__ ebin) {
    __shared__ int cur[NB];
    const int t = threadIdx.x;
    for (int b = t; b < NB; b += 256)
        cur[b] = bstart[b] + blk_off[blockIdx.x * NB + b];
    __syncthreads();
    const int base = blockIdx.x * EPB;
#pragma unroll 4
    for (int i = 0; i < EPB / 256; ++i) {
        int e = base + i * 256 + t;
        if (e < NE) {
            int s = ei[e];       // src (< 2^17)
            int d = ei[NE + e];  // dst
            int p = atomicAdd(&cur[d >> 9], 1);
            ebin[p] = ((d & 511) << 23) | s;  // pack local-dst | src
        }
    }
}

__global__ __launch_bounds__(512) void p4_finalize(const int* __restrict__ bstart,
                                                   const int* __restrict__ ebin,
                                                   int* __restrict__ esrc,
                                                   int* __restrict__ rowstart,
                                                   float* __restrict__ dinv) {
    __shared__ int lh[512];  // local degree
    __shared__ int sc[512];  // scan buffer
    __shared__ int lc[512];  // local cursor
    const int t = threadIdx.x;
    const int b = blockIdx.x;
    const int n0 = b << 9;
    const int ebase = bstart[b];
    const int ecnt = bstart[b + 1] - ebase;
    lh[t] = 0;
    __syncthreads();
    for (int i = t; i < ecnt; i += 512)
        atomicAdd(&lh[((unsigned)ebin[ebase + i]) >> 23], 1);
    __syncthreads();
    const int c = lh[t];
    sc[t] = c;
    __syncthreads();
    for (int off = 1; off < 512; off <<= 1) {
        int v = (t >= off) ? sc[t - off] : 0;
        __syncthreads();
        sc[t] += v;
        __syncthreads();
    }
    const int excl = ebase + sc[t] - c;  // global rowstart for node n0+t
    lc[t] = excl;
    const int node = n0 + t;
    if (node < NN) {
        rowstart[node] = excl;
        dinv[node] = rsqrtf((float)c + 1.0f);  // deg includes self-loop
    }
    if (b == NB - 1 && t == 0) rowstart[NN] = NE;
    __syncthreads();
    for (int i = t; i < ecnt; i += 512) {
        int v = ebin[ebase + i];
        int p = atomicAdd(&lc[((unsigned)v) >> 23], 1);
        esrc[p] = v & 0x7FFFFF;  // writes land in a 65KB L2-hot window
    }
}

// ---------------- input projection: h = relu(x @ W_in + b_in) ----------------

__global__ __launch_bounds__(256) void inproj_kernel(const float* __restrict__ x,
                                                     const float* __restrict__ W_in,
                                                     const float* __restrict__ b_in,
                                                     float* __restrict__ hA) {
    int n = blockIdx.x * 2 + (threadIdx.x >> 7);
    int j = threadIdx.x & 127;
    float acc = b_in[j];
#pragma unroll
    for (int f = 0; f < FI; ++f) acc += x[n * FI + f] * W_in[f * HD + j];
    hA[n * HD + j] = fmaxf(acc, 0.f);
}

// ---------------- GEMM: B[N,DO](bf16) = A[N,128](f32) @ W[128,DO](f32) ------
// 16 nodes x DO cols per 256-thread block; k unrolled by 4; bf16 epilogue.

template <int DO>
__global__ __launch_bounds__(256) void gemm_kernel(const float* __restrict__ A,
                                                   const float* __restrict__ W,
                                                   unsigned short* __restrict__ B) {
    constexpr int NPB = 16;
    constexpr int GROUPS = 256 / DO;   // 2 (DO=128) or 4 (DO=64)
    constexpr int NPT = NPB / GROUPS;  // 8 or 4
    __shared__ float sh[NPB][HD];
    const int tid = threadIdx.x;
    const int n0 = blockIdx.x * NPB;
    for (int i = tid; i < NPB * HD / 4; i += 256) {
        int r = i >> 5, kq = i & 31;
        ((float4*)&sh[r][0])[kq] = ((const float4*)(A + (size_t)(n0 + r) * HD))[kq];
    }
    __syncthreads();
    const int col = tid % DO;
    const int grp = tid / DO;
    float acc[NPT];
#pragma unroll
    for (int i = 0; i < NPT; ++i) acc[i] = 0.f;
    for (int k4 = 0; k4 < HD / 4; ++k4) {
        const float w0 = W[(k4 * 4 + 0) * DO + col];
        const float w1 = W[(k4 * 4 + 1) * DO + col];
        const float w2 = W[(k4 * 4 + 2) * DO + col];
        const float w3 = W[(k4 * 4 + 3) * DO + col];
#pragma unroll
        for (int i = 0; i < NPT; ++i) {
            const float4 a = *(const float4*)&sh[grp * NPT + i][k4 * 4];
            acc[i] += a.x * w0 + a.y * w1 + a.z * w2 + a.w * w3;
        }
    }
#pragma unroll
    for (int i = 0; i < NPT; ++i)
        B[(size_t)(n0 + grp * NPT + i) * DO + col] = f2bf(acc[i]);
}

// ---------- fused gather + self-loop + bias + BN (+ ReLU + residual) ----------
// One block (128 thr) per dst node. hXW is bf16 [N, DO]; fp32 accumulate.
// thread t: col-quad q=t&(QN-1) (8B ushort4 loads), edge-group grp=t/QN.
// MUST be launched with 128 threads (edge tile size == 128).

template <int DO, bool RELU_RES>
__global__ __launch_bounds__(128) void gather_kernel(const unsigned short* __restrict__ hXW,
                                                     float* __restrict__ resOut,
                                                     const int* __restrict__ rowstart,
                                                     const int* __restrict__ esrc,
                                                     const float* __restrict__ dinv,
                                                     const float* __restrict__ bias,
                                                     const float* __restrict__ g,
                                                     const float* __restrict__ be,
                                                     const float* __restrict__ m,
                                                     const float* __restrict__ v) {
    constexpr int QN = DO / 4;        // 32 (DO=128) or 16 (DO=64) col-quads
    constexpr int NG = 128 / QN;      // 4 or 8 edge groups
    __shared__ int s_idx[128];
    __shared__ float s_dv[128];
    __shared__ float4 s_red[128];
    const int n = blockIdx.x;
    const int t = threadIdx.x;
    const int rs = rowstart[n];
    const int re = rowstart[n + 1];
    const float dn = dinv[n];
    const int q = t & (QN - 1);
    const int grp = t / QN;
    float4 acc0 = {0.f, 0.f, 0.f, 0.f};
    float4 acc1 = {0.f, 0.f, 0.f, 0.f};
    for (int base = rs; base < re; base += 128) {
        const int c = min(128, re - base);
        __syncthreads();
        if (t < c) {
            int s = esrc[base + t];
            s_idx[t] = s;
            s_dv[t] = dinv[s];
        }
        __syncthreads();
        for (int j = grp; j < c; j += 2 * NG) {
            {
                const ushort4 hv = *(const ushort4*)(hXW + (size_t)s_idx[j] * DO + q * 4);
                const float w = s_dv[j];
                acc0.x += bf2f(hv.x) * w; acc0.y += bf2f(hv.y) * w;
                acc0.z += bf2f(hv.z) * w; acc0.w += bf2f(hv.w) * w;
            }
            if (j + NG < c) {
                const ushort4 hv = *(const ushort4*)(hXW + (size_t)s_idx[j + NG] * DO + q * 4);
                const float w = s_dv[j + NG];
                acc1.x += bf2f(hv.x) * w; acc1.y += bf2f(hv.y) * w;
                acc1.z += bf2f(hv.z) * w; acc1.w += bf2f(hv.w) * w;
            }
        }
    }
    acc0.x += acc1.x; acc0.y += acc1.y; acc0.z += acc1.z; acc0.w += acc1.w;
    s_red[t] = acc0;
    __syncthreads();
    if (t < QN) {
        float4 sum = s_red[t];
#pragma unroll
        for (int k = 1; k < NG; ++k) {
            const float4 a = s_red[t + k * QN];
            sum.x += a.x; sum.y += a.y; sum.z += a.z; sum.w += a.w;
        }
        const ushort4 sf = *(const ushort4*)(hXW + (size_t)n * DO + t * 4);
        const float4 b4 = *(const float4*)(bias + t * 4);
        const float4 g4 = *(const float4*)(g + t * 4);
        const float4 be4 = *(const float4*)(be + t * 4);
        const float4 m4 = *(const float4*)(m + t * 4);
        const float4 v4 = *(const float4*)(v + t * 4);
        float4 val;
        val.x = (sum.x + dn * bf2f(sf.x)) * dn + b4.x;
        val.y = (sum.y + dn * bf2f(sf.y)) * dn + b4.y;
        val.z = (sum.z + dn * bf2f(sf.z)) * dn + b4.z;
        val.w = (sum.w + dn * bf2f(sf.w)) * dn + b4.w;
        val.x = (val.x - m4.x) * (g4.x * rsqrtf(v4.x + EPS)) + be4.x;
        val.y = (val.y - m4.y) * (g4.y * rsqrtf(v4.y + EPS)) + be4.y;
        val.z = (val.z - m4.z) * (g4.z * rsqrtf(v4.z + EPS)) + be4.z;
        val.w = (val.w - m4.w) * (g4.w * rsqrtf(v4.w + EPS)) + be4.w;
        float4* outp = (float4*)(resOut + (size_t)n * DO + t * 4);
        if (RELU_RES) {
            const float4 r = *outp;
            val.x = fmaxf(val.x, 0.f) + r.x;
            val.y = fmaxf(val.y, 0.f) + r.y;
            val.z = fmaxf(val.z, 0.f) + r.z;
            val.w = fmaxf(val.w, 0.f) + r.w;
        }
        *outp = val;
    }
}

// ---------------- launch ----------------

extern "C" void kernel_launch(void* const* d_in, const int* in_sizes, int n_in,
                              void* d_out, int out_size, void* d_ws, size_t ws_size,
                              hipStream_t stream) {
    const float* x    = (const float*)d_in[0];
    const int*   ei   = (const int*)d_in[1];
    const float* W_in = (const float*)d_in[2];
    const float* b_in = (const float*)d_in[3];
    const float* Wl[3] = {(const float*)d_in[4], (const float*)d_in[10], (const float*)d_in[16]};
    const float* bl[3] = {(const float*)d_in[5], (const float*)d_in[11], (const float*)d_in[17]};
    const float* gl[3] = {(const float*)d_in[6], (const float*)d_in[12], (const float*)d_in[18]};
    const float* bel[3] = {(const float*)d_in[7], (const float*)d_in[13], (const float*)d_in[19]};
    const float* ml[3] = {(const float*)d_in[8], (const float*)d_in[14], (const float*)d_in[20]};
    const float* vl[3] = {(const float*)d_in[9], (const float*)d_in[15], (const float*)d_in[21]};
    float* out = (float*)d_out;

    char* ws = (char*)d_ws;
    size_t off = 0;
    auto carve = [&](size_t bytes) {
        void* p = ws + off;
        off += (bytes + 255) & ~(size_t)255;
        return p;
    };
    int*   bcnt     = (int*)carve(NB * sizeof(int));
    int*   bstart   = (int*)carve((NB + 1) * sizeof(int));
    int*   blk_off  = (int*)carve((size_t)NBLK * NB * sizeof(int));
    int*   rowstart = (int*)carve((NN + 1) * sizeof(int));
    float* dinv     = (float*)carve(NN * sizeof(float));
    int*   esrc     = (int*)carve((size_t)NE * sizeof(int));
    float* hA       = (float*)carve((size_t)NN * HD * sizeof(float));
    unsigned short* hB = (unsigned short*)carve((size_t)NN * HD * sizeof(unsigned short));
    int*   ebin     = (int*)carve((size_t)NE * sizeof(int));
    (void)ws_size;

    hipMemsetAsync(bcnt, 0, NB * sizeof(int), stream);

    p1_bucket_hist<<<NBLK, 256, 0, stream>>>(ei, bcnt, blk_off);
    p2_bucket_scan<<<1, 256, 0, stream>>>(bcnt, bstart);
    p3_bin<<<NBLK, 256, 0, stream>>>(ei, bstart, blk_off, ebin);
    p4_finalize<<<NB, 512, 0, stream>>>(bstart, ebin, esrc, rowstart, dinv);

    inproj_kernel<<<NN / 2, 256, 0, stream>>>(x, W_in, b_in, hA);

    // layer 0
    gemm_kernel<128><<<NN / 16, 256, 0, stream>>>(hA, Wl[0], hB);
    gather_kernel<128, true><<<NN, 128, 0, stream>>>(hB, hA, rowstart, esrc, dinv,
                                                     bl[0], gl[0], bel[0], ml[0], vl[0]);
    // layer 1
    gemm_kernel<128><<<NN / 16, 256, 0, stream>>>(hA, Wl[1], hB);
    gather_kernel<128, true><<<NN, 128, 0, stream>>>(hB, hA, rowstart, esrc, dinv,
                                                     bl[1], gl[1], bel[1], ml[1], vl[1]);
    // layer 2 (BN only, write d_out); 128 threads (edge tile = 128)
    gemm_kernel<64><<<NN / 16, 256, 0, stream>>>(hA, Wl[2], hB);
    gather_kernel<64, false><<<NN, 128, 0, stream>>>(hB, out, rowstart, esrc, dinv,
                                                     bl[2], gl[2], bel[2], ml[2], vl[2]);
}

// Round 6
// 677.306 us; speedup vs baseline: 2.3631x; 1.0996x over previous
//
#include <hip/hip_runtime.h>

// NuclideGNN: 3-layer GCN on MI355X.
// R5: store GEMM product hB (XW) as fp8 e4m3 (OCP, HW cvt) -> gather payload
//     12.8MB fits aggregate L2 better; fetch/edge drops ~2x again. fp32
//     accumulate; residual stream hA stays fp32.
// Pipeline: P1 -> P2 -> P3 -> P4 -> inproj -> [gemm(fp8 out) -> gather]x3

#define NN 100000
#define NE 3200000
#define FI 7
#define HD 128
#define DD 64
#define EPS 1e-5f
#define NB 196                        // buckets of 512 dst nodes (dst>>9)
#define EPB 8192                      // edges per P1/P3 block (256 thr x 32)
#define NBLK ((NE + EPB - 1) / EPB)   // 391

typedef float float2v __attribute__((ext_vector_type(2)));

__device__ __forceinline__ unsigned char f2fp8(float f) {
    // OCP e4m3fn via HW packed cvt; take low byte
    return (unsigned char)(__builtin_amdgcn_cvt_pk_fp8_f32(f, f, 0, false) & 0xFF);
}

// ---------------- CSR build: two-level bucket sort ----------------

__global__ __launch_bounds__(256) void p1_bucket_hist(const int* __restrict__ ei,
                                                      int* __restrict__ bcnt,
                                                      int* __restrict__ blk_off) {
    __shared__ int h[NB];
    const int t = threadIdx.x;
    for (int b = t; b < NB; b += 256) h[b] = 0;
    __syncthreads();
    const int base = blockIdx.x * EPB;
#pragma unroll 4
    for (int i = 0; i < EPB / 256; ++i) {
        int e = base + i * 256 + t;
        if (e < NE) atomicAdd(&h[ei[NE + e] >> 9], 1);
    }
    __syncthreads();
    for (int b = t; b < NB; b += 256) {
        int c = h[b];
        blk_off[blockIdx.x * NB + b] = c ? atomicAdd(&bcnt[b], c) : 0;
    }
}

__global__ __launch_bounds__(256) void p2_bucket_scan(const int* __restrict__ bcnt,
                                                      int* __restrict__ bstart) {
    __shared__ int sh[256];
    const int t = threadIdx.x;
    const int myc = (t < NB) ? bcnt[t] : 0;
    sh[t] = myc;
    __syncthreads();
    for (int off = 1; off < 256; off <<= 1) {
        int v = (t >= off) ? sh[t - off] : 0;
        __syncthreads();
        sh[t] += v;
        __syncthreads();
    }
    if (t < NB) bstart[t] = sh[t] - myc;  // exclusive prefix
    if (t == 0) bstart[NB] = NE;
}

__global__ __launch_bounds__(256) void p3_bin(const int* __restrict__ ei,
                                              const int* __restrict__ bstart,
                                              const int* __restrict__ blk_off,
                                              int* __restrict__ ebin) {
    __shared__ int cur[NB];
    const int t = threadIdx.x;
    for (int b = t; b < NB; b += 256)
        cur[b] = bstart[b] + blk_off[blockIdx.x * NB + b];
    __syncthreads();
    const int base = blockIdx.x * EPB;
#pragma unroll 4
    for (int i = 0; i < EPB / 256; ++i) {
        int e = base + i * 256 + t;
        if (e < NE) {
            int s = ei[e];       // src (< 2^17)
            int d = ei[NE + e];  // dst
            int p = atomicAdd(&cur[d >> 9], 1);
            ebin[p] = ((d & 511) << 23) | s;  // pack local-dst | src
        }
    }
}

__global__ __launch_bounds__(512) void p4_finalize(const int* __restrict__ bstart,
                                                   const int* __restrict__ ebin,
                                                   int* __restrict__ esrc,
                                                   int* __restrict__ rowstart,
                                                   float* __restrict__ dinv) {
    __shared__ int lh[512];  // local degree
    __shared__ int sc[512];  // scan buffer
    __shared__ int lc[512];  // local cursor
    const int t = threadIdx.x;
    const int b = blockIdx.x;
    const int n0 = b << 9;
    const int ebase = bstart[b];
    const int ecnt = bstart[b + 1] - ebase;
    lh[t] = 0;
    __syncthreads();
    for (int i = t; i < ecnt; i += 512)
        atomicAdd(&lh[((unsigned)ebin[ebase + i]) >> 23], 1);
    __syncthreads();
    const int c = lh[t];
    sc[t] = c;
    __syncthreads();
    for (int off = 1; off < 512; off <<= 1) {
        int v = (t >= off) ? sc[t - off] : 0;
        __syncthreads();
        sc[t] += v;
        __syncthreads();
    }
    const int excl = ebase + sc[t] - c;  // global rowstart for node n0+t
    lc[t] = excl;
    const int node = n0 + t;
    if (node < NN) {
        rowstart[node] = excl;
        dinv[node] = rsqrtf((float)c + 1.0f);  // deg includes self-loop
    }
    if (b == NB - 1 && t == 0) rowstart[NN] = NE;
    __syncthreads();
    for (int i = t; i < ecnt; i += 512) {
        int v = ebin[ebase + i];
        int p = atomicAdd(&lc[((unsigned)v) >> 23], 1);
        esrc[p] = v & 0x7FFFFF;  // writes land in a 65KB L2-hot window
    }
}

// ---------------- input projection: h = relu(x @ W_in + b_in) ----------------

__global__ __launch_bounds__(256) void inproj_kernel(const float* __restrict__ x,
                                                     const float* __restrict__ W_in,
                                                     const float* __restrict__ b_in,
                                                     float* __restrict__ hA) {
    int n = blockIdx.x * 2 + (threadIdx.x >> 7);
    int j = threadIdx.x & 127;
    float acc = b_in[j];
#pragma unroll
    for (int f = 0; f < FI; ++f) acc += x[n * FI + f] * W_in[f * HD + j];
    hA[n * HD + j] = fmaxf(acc, 0.f);
}

// ---------------- GEMM: B[N,DO](fp8) = A[N,128](f32) @ W[128,DO](f32) -------
// 16 nodes x DO cols per 256-thread block; k unrolled by 4; fp8 epilogue.

template <int DO>
__global__ __launch_bounds__(256) void gemm_kernel(const float* __restrict__ A,
                                                   const float* __restrict__ W,
                                                   unsigned char* __restrict__ B) {
    constexpr int NPB = 16;
    constexpr int GROUPS = 256 / DO;   // 2 (DO=128) or 4 (DO=64)
    constexpr int NPT = NPB / GROUPS;  // 8 or 4
    __shared__ float sh[NPB][HD];
    const int tid = threadIdx.x;
    const int n0 = blockIdx.x * NPB;
    for (int i = tid; i < NPB * HD / 4; i += 256) {
        int r = i >> 5, kq = i & 31;
        ((float4*)&sh[r][0])[kq] = ((const float4*)(A + (size_t)(n0 + r) * HD))[kq];
    }
    __syncthreads();
    const int col = tid % DO;
    const int grp = tid / DO;
    float acc[NPT];
#pragma unroll
    for (int i = 0; i < NPT; ++i) acc[i] = 0.f;
    for (int k4 = 0; k4 < HD / 4; ++k4) {
        const float w0 = W[(k4 * 4 + 0) * DO + col];
        const float w1 = W[(k4 * 4 + 1) * DO + col];
        const float w2 = W[(k4 * 4 + 2) * DO + col];
        const float w3 = W[(k4 * 4 + 3) * DO + col];
#pragma unroll
        for (int i = 0; i < NPT; ++i) {
            const float4 a = *(const float4*)&sh[grp * NPT + i][k4 * 4];
            acc[i] += a.x * w0 + a.y * w1 + a.z * w2 + a.w * w3;
        }
    }
#pragma unroll
    for (int i = 0; i < NPT; ++i)
        B[(size_t)(n0 + grp * NPT + i) * DO + col] = f2fp8(acc[i]);
}

// ---------- fused gather + self-loop + bias + BN (+ ReLU + residual) ----------
// One block (128 thr) per dst node. hXW is fp8 e4m3 [N, DO]; fp32 accumulate.
// thread t: col-quad q=t&(QN-1) (4B uint loads -> 2x cvt_pk_f32_fp8),
// edge-group grp=t/QN. MUST be launched with 128 threads (edge tile == 128).

template <int DO, bool RELU_RES>
__global__ __launch_bounds__(128) void gather_kernel(const unsigned char* __restrict__ hXW,
                                                     float* __restrict__ resOut,
                                                     const int* __restrict__ rowstart,
                                                     const int* __restrict__ esrc,
                                                     const float* __restrict__ dinv,
                                                     const float* __restrict__ bias,
                                                     const float* __restrict__ g,
                                                     const float* __restrict__ be,
                                                     const float* __restrict__ m,
                                                     const float* __restrict__ v) {
    constexpr int QN = DO / 4;        // 32 (DO=128) or 16 (DO=64) col-quads
    constexpr int NG = 128 / QN;      // 4 or 8 edge groups
    __shared__ int s_idx[128];
    __shared__ float s_dv[128];
    __shared__ float4 s_red[128];
    const int n = blockIdx.x;
    const int t = threadIdx.x;
    const int rs = rowstart[n];
    const int re = rowstart[n + 1];
    const float dn = dinv[n];
    const int q = t & (QN - 1);
    const int grp = t / QN;
    float4 acc0 = {0.f, 0.f, 0.f, 0.f};
    float4 acc1 = {0.f, 0.f, 0.f, 0.f};
    for (int base = rs; base < re; base += 128) {
        const int c = min(128, re - base);
        __syncthreads();
        if (t < c) {
            int s = esrc[base + t];
            s_idx[t] = s;
            s_dv[t] = dinv[s];
        }
        __syncthreads();
        for (int j = grp; j < c; j += 2 * NG) {
            {
                const unsigned u = *(const unsigned*)(hXW + (size_t)s_idx[j] * DO + q * 4);
                const float w = s_dv[j];
                const float2v lo = __builtin_amdgcn_cvt_pk_f32_fp8(u, false);
                const float2v hi = __builtin_amdgcn_cvt_pk_f32_fp8(u, true);
                acc0.x += lo.x * w; acc0.y += lo.y * w;
                acc0.z += hi.x * w; acc0.w += hi.y * w;
            }
            if (j + NG < c) {
                const unsigned u = *(const unsigned*)(hXW + (size_t)s_idx[j + NG] * DO + q * 4);
                const float w = s_dv[j + NG];
                const float2v lo = __builtin_amdgcn_cvt_pk_f32_fp8(u, false);
                const float2v hi = __builtin_amdgcn_cvt_pk_f32_fp8(u, true);
                acc1.x += lo.x * w; acc1.y += lo.y * w;
                acc1.z += hi.x * w; acc1.w += hi.y * w;
            }
        }
    }
    acc0.x += acc1.x; acc0.y += acc1.y; acc0.z += acc1.z; acc0.w += acc1.w;
    s_red[t] = acc0;
    __syncthreads();
    if (t < QN) {
        float4 sum = s_red[t];
#pragma unroll
        for (int k = 1; k < NG; ++k) {
            const float4 a = s_red[t + k * QN];
            sum.x += a.x; sum.y += a.y; sum.z += a.z; sum.w += a.w;
        }
        const unsigned su = *(const unsigned*)(hXW + (size_t)n * DO + t * 4);
        const float2v slo = __builtin_amdgcn_cvt_pk_f32_fp8(su, false);
        const float2v shi = __builtin_amdgcn_cvt_pk_f32_fp8(su, true);
        const float4 b4 = *(const float4*)(bias + t * 4);
        const float4 g4 = *(const float4*)(g + t * 4);
        const float4 be4 = *(const float4*)(be + t * 4);
        const float4 m4 = *(const float4*)(m + t * 4);
        const float4 v4 = *(const float4*)(v + t * 4);
        float4 val;
        val.x = (sum.x + dn * slo.x) * dn + b4.x;
        val.y = (sum.y + dn * slo.y) * dn + b4.y;
        val.z = (sum.z + dn * shi.x) * dn + b4.z;
        val.w = (sum.w + dn * shi.y) * dn + b4.w;
        val.x = (val.x - m4.x) * (g4.x * rsqrtf(v4.x + EPS)) + be4.x;
        val.y = (val.y - m4.y) * (g4.y * rsqrtf(v4.y + EPS)) + be4.y;
        val.z = (val.z - m4.z) * (g4.z * rsqrtf(v4.z + EPS)) + be4.z;
        val.w = (val.w - m4.w) * (g4.w * rsqrtf(v4.w + EPS)) + be4.w;
        float4* outp = (float4*)(resOut + (size_t)n * DO + t * 4);
        if (RELU_RES) {
            const float4 r = *outp;
            val.x = fmaxf(val.x, 0.f) + r.x;
            val.y = fmaxf(val.y, 0.f) + r.y;
            val.z = fmaxf(val.z, 0.f) + r.z;
            val.w = fmaxf(val.w, 0.f) + r.w;
        }
        *outp = val;
    }
}

// ---------------- launch ----------------

extern "C" void kernel_launch(void* const* d_in, const int* in_sizes, int n_in,
                              void* d_out, int out_size, void* d_ws, size_t ws_size,
                              hipStream_t stream) {
    const float* x    = (const float*)d_in[0];
    const int*   ei   = (const int*)d_in[1];
    const float* W_in = (const float*)d_in[2];
    const float* b_in = (const float*)d_in[3];
    const float* Wl[3] = {(const float*)d_in[4], (const float*)d_in[10], (const float*)d_in[16]};
    const float* bl[3] = {(const float*)d_in[5], (const float*)d_in[11], (const float*)d_in[17]};
    const float* gl[3] = {(const float*)d_in[6], (const float*)d_in[12], (const float*)d_in[18]};
    const float* bel[3] = {(const float*)d_in[7], (const float*)d_in[13], (const float*)d_in[19]};
    const float* ml[3] = {(const float*)d_in[8], (const float*)d_in[14], (const float*)d_in[20]};
    const float* vl[3] = {(const float*)d_in[9], (const float*)d_in[15], (const float*)d_in[21]};
    float* out = (float*)d_out;

    char* ws = (char*)d_ws;
    size_t off = 0;
    auto carve = [&](size_t bytes) {
        void* p = ws + off;
        off += (bytes + 255) & ~(size_t)255;
        return p;
    };
    int*   bcnt     = (int*)carve(NB * sizeof(int));
    int*   bstart   = (int*)carve((NB + 1) * sizeof(int));
    int*   blk_off  = (int*)carve((size_t)NBLK * NB * sizeof(int));
    int*   rowstart = (int*)carve((NN + 1) * sizeof(int));
    float* dinv     = (float*)carve(NN * sizeof(float));
    int*   esrc     = (int*)carve((size_t)NE * sizeof(int));
    float* hA       = (float*)carve((size_t)NN * HD * sizeof(float));
    unsigned char* hB = (unsigned char*)carve((size_t)NN * HD);
    int*   ebin     = (int*)carve((size_t)NE * sizeof(int));
    (void)ws_size;

    hipMemsetAsync(bcnt, 0, NB * sizeof(int), stream);

    p1_bucket_hist<<<NBLK, 256, 0, stream>>>(ei, bcnt, blk_off);
    p2_bucket_scan<<<1, 256, 0, stream>>>(bcnt, bstart);
    p3_bin<<<NBLK, 256, 0, stream>>>(ei, bstart, blk_off, ebin);
    p4_finalize<<<NB, 512, 0, stream>>>(bstart, ebin, esrc, rowstart, dinv);

    inproj_kernel<<<NN / 2, 256, 0, stream>>>(x, W_in, b_in, hA);

    // layer 0
    gemm_kernel<128><<<NN / 16, 256, 0, stream>>>(hA, Wl[0], hB);
    gather_kernel<128, true><<<NN, 128, 0, stream>>>(hB, hA, rowstart, esrc, dinv,
                                                     bl[0], gl[0], bel[0], ml[0], vl[0]);
    // layer 1
    gemm_kernel<128><<<NN / 16, 256, 0, stream>>>(hA, Wl[1], hB);
    gather_kernel<128, true><<<NN, 128, 0, stream>>>(hB, hA, rowstart, esrc, dinv,
                                                     bl[1], gl[1], bel[1], ml[1], vl[1]);
    // layer 2 (BN only, write d_out); 128 threads (edge tile = 128)
    gemm_kernel<64><<<NN / 16, 256, 0, stream>>>(hA, Wl[2], hB);
    gather_kernel<64, false><<<NN, 128, 0, stream>>>(hB, out, rowstart, esrc, dinv,
                                                     bl[2], gl[2], bel[2], ml[2], vl[2]);
}

// Round 7
// 534.654 us; speedup vs baseline: 2.9936x; 1.2668x over previous
//
#include <hip/hip_runtime.h>

// NuclideGNN: 3-layer GCN on MI355X.
// R6: (a) MFMA GEMM (16x16x32 bf16, pre-swizzled W frags, fp8 epilogue) —
//     bf16 input noise is negligible vs fp8 output quantization;
//     (b) gather widened to 8 cols/thread (uint2 loads) for 2x MLP bytes.
//     fp32 residual stream hA + bf16 shadow hAbf (GEMM input only).

#define NN 100000
#define NE 3200000
#define FI 7
#define HD 128
#define DD 64
#define EPS 1e-5f
#define NB 196                        // buckets of 512 dst nodes (dst>>9)
#define EPB 8192                      // edges per P1/P3 block (256 thr x 32)
#define NBLK ((NE + EPB - 1) / EPB)   // 391

typedef float float2v __attribute__((ext_vector_type(2)));
typedef short short8 __attribute__((ext_vector_type(8)));
typedef float f32x4 __attribute__((ext_vector_type(4)));

__device__ __forceinline__ unsigned char f2fp8(float f) {
    return (unsigned char)(__builtin_amdgcn_cvt_pk_fp8_f32(f, f, 0, false) & 0xFF);
}
__device__ __forceinline__ unsigned short f2bf(float f) {
    unsigned u = __float_as_uint(f);
    u += 0x7FFF + ((u >> 16) & 1);  // RNE
    return (unsigned short)(u >> 16);
}

// ---------------- CSR build: two-level bucket sort ----------------

__global__ __launch_bounds__(256) void p1_bucket_hist(const int* __restrict__ ei,
                                                      int* __restrict__ bcnt,
                                                      int* __restrict__ blk_off) {
    __shared__ int h[NB];
    const int t = threadIdx.x;
    for (int b = t; b < NB; b += 256) h[b] = 0;
    __syncthreads();
    const int base = blockIdx.x * EPB;
#pragma unroll 4
    for (int i = 0; i < EPB / 256; ++i) {
        int e = base + i * 256 + t;
        if (e < NE) atomicAdd(&h[ei[NE + e] >> 9], 1);
    }
    __syncthreads();
    for (int b = t; b < NB; b += 256) {
        int c = h[b];
        blk_off[blockIdx.x * NB + b] = c ? atomicAdd(&bcnt[b], c) : 0;
    }
}

__global__ __launch_bounds__(256) void p2_bucket_scan(const int* __restrict__ bcnt,
                                                      int* __restrict__ bstart) {
    __shared__ int sh[256];
    const int t = threadIdx.x;
    const int myc = (t < NB) ? bcnt[t] : 0;
    sh[t] = myc;
    __syncthreads();
    for (int off = 1; off < 256; off <<= 1) {
        int v = (t >= off) ? sh[t - off] : 0;
        __syncthreads();
        sh[t] += v;
        __syncthreads();
    }
    if (t < NB) bstart[t] = sh[t] - myc;  // exclusive prefix
    if (t == 0) bstart[NB] = NE;
}

__global__ __launch_bounds__(256) void p3_bin(const int* __restrict__ ei,
                                              const int* __restrict__ bstart,
                                              const int* __restrict__ blk_off,
                                              int* __restrict__ ebin) {
    __shared__ int cur[NB];
    const int t = threadIdx.x;
    for (int b = t; b < NB; b += 256)
        cur[b] = bstart[b] + blk_off[blockIdx.x * NB + b];
    __syncthreads();
    const int base = blockIdx.x * EPB;
#pragma unroll 4
    for (int i = 0; i < EPB / 256; ++i) {
        int e = base + i * 256 + t;
        if (e < NE) {
            int s = ei[e];       // src (< 2^17)
            int d = ei[NE + e];  // dst
            int p = atomicAdd(&cur[d >> 9], 1);
            ebin[p] = ((d & 511) << 23) | s;  // pack local-dst | src
        }
    }
}

__global__ __launch_bounds__(512) void p4_finalize(const int* __restrict__ bstart,
                                                   const int* __restrict__ ebin,
                                                   int* __restrict__ esrc,
                                                   int* __restrict__ rowstart,
                                                   float* __restrict__ dinv) {
    __shared__ int lh[512];  // local degree
    __shared__ int sc[512];  // scan buffer
    __shared__ int lc[512];  // local cursor
    const int t = threadIdx.x;
    const int b = blockIdx.x;
    const int n0 = b << 9;
    const int ebase = bstart[b];
    const int ecnt = bstart[b + 1] - ebase;
    lh[t] = 0;
    __syncthreads();
    for (int i = t; i < ecnt; i += 512)
        atomicAdd(&lh[((unsigned)ebin[ebase + i]) >> 23], 1);
    __syncthreads();
    const int c = lh[t];
    sc[t] = c;
    __syncthreads();
    for (int off = 1; off < 512; off <<= 1) {
        int v = (t >= off) ? sc[t - off] : 0;
        __syncthreads();
        sc[t] += v;
        __syncthreads();
    }
    const int excl = ebase + sc[t] - c;  // global rowstart for node n0+t
    lc[t] = excl;
    const int node = n0 + t;
    if (node < NN) {
        rowstart[node] = excl;
        dinv[node] = rsqrtf((float)c + 1.0f);  // deg includes self-loop
    }
    if (b == NB - 1 && t == 0) rowstart[NN] = NE;
    __syncthreads();
    for (int i = t; i < ecnt; i += 512) {
        int v = ebin[ebase + i];
        int p = atomicAdd(&lc[((unsigned)v) >> 23], 1);
        esrc[p] = v & 0x7FFFFF;  // writes land in a 65KB L2-hot window
    }
}

// --------- input projection: h = relu(x @ W_in + b_in), fp32 + bf16 ---------

__global__ __launch_bounds__(256) void inproj_kernel(const float* __restrict__ x,
                                                     const float* __restrict__ W_in,
                                                     const float* __restrict__ b_in,
                                                     float* __restrict__ hA,
                                                     unsigned short* __restrict__ hAbf) {
    int n = blockIdx.x * 2 + (threadIdx.x >> 7);
    int j = threadIdx.x & 127;
    float acc = b_in[j];
#pragma unroll
    for (int f = 0; f < FI; ++f) acc += x[n * FI + f] * W_in[f * HD + j];
    acc = fmaxf(acc, 0.f);
    hA[n * HD + j] = acc;
    hAbf[n * HD + j] = f2bf(acc);
}

// -------- W pre-swizzle into MFMA B-fragment order (bf16) -------------------
// B-frag for lane l, coltile nt, kstep ks: W[ks*32+(l>>4)*8+j][nt*16+(l&15)],
// j=0..7 packed contiguously. grid = (DO/16)*4 blocks of 64 thr.

template <int DO>
__global__ __launch_bounds__(64) void wprep(const float* __restrict__ W,
                                            unsigned short* __restrict__ Wf) {
    const int lane = threadIdx.x;
    const int nt = blockIdx.x >> 2;
    const int ks = blockIdx.x & 3;
    short8 o;
#pragma unroll
    for (int j = 0; j < 8; ++j)
        o[j] = (short)f2bf(W[(ks * 32 + (lane >> 4) * 8 + j) * DO + nt * 16 + (lane & 15)]);
    *(short8*)(Wf + ((size_t)blockIdx.x * 64 + lane) * 8) = o;
}

// -------- MFMA GEMM: B[N,DO](fp8) = A[N,128](bf16) @ W(bf16 frags) ----------
// 32 nodes x DO cols per 256-thr block (4 waves). Wave w covers col-tiles
// [w*CT, w*CT+CT). A-frags loaded straight from global (L1/L2-hot rows).

template <int DO>
__global__ __launch_bounds__(256) void gemm_mfma(const unsigned short* __restrict__ A,
                                                 const unsigned short* __restrict__ Wf,
                                                 unsigned char* __restrict__ B) {
    constexpr int CT = DO / 64;  // col-tiles per wave: 2 (DO=128) or 1 (DO=64)
    const int tid = threadIdx.x;
    const int wave = tid >> 6;
    const int lane = tid & 63;
    const int n0 = blockIdx.x * 32;
    short8 bfrag[CT][4];
#pragma unroll
    for (int ct = 0; ct < CT; ++ct)
#pragma unroll
        for (int ks = 0; ks < 4; ++ks)
            bfrag[ct][ks] = *(const short8*)(Wf + ((size_t)(((wave * CT + ct) * 4 + ks) * 64) + lane) * 8);
#pragma unroll
    for (int rt = 0; rt < 2; ++rt) {
        const int arow = n0 + rt * 16 + (lane & 15);
        short8 afrag[4];
#pragma unroll
        for (int ks = 0; ks < 4; ++ks)
            afrag[ks] = *(const short8*)(A + (size_t)arow * HD + ks * 32 + ((lane >> 4) & 3) * 8);
        f32x4 acc[CT];
#pragma unroll
        for (int ct = 0; ct < CT; ++ct) acc[ct] = (f32x4){0.f, 0.f, 0.f, 0.f};
#pragma unroll
        for (int ks = 0; ks < 4; ++ks)
#pragma unroll
            for (int ct = 0; ct < CT; ++ct)
                acc[ct] = __builtin_amdgcn_mfma_f32_16x16x32_bf16(afrag[ks], bfrag[ct][ks], acc[ct], 0, 0, 0);
#pragma unroll
        for (int ct = 0; ct < CT; ++ct) {
            const int ocol = (wave * CT + ct) * 16 + (lane & 15);
#pragma unroll
            for (int r = 0; r < 4; ++r) {
                const int orow = n0 + rt * 16 + (lane >> 4) * 4 + r;
                B[(size_t)orow * DO + ocol] = f2fp8(acc[ct][r]);
            }
        }
    }
}

// ---------- fused gather + self-loop + bias + BN (+ ReLU + residual) ----------
// One block (128 thr) per dst node. hXW fp8 e4m3 [N, DO]; fp32 accumulate.
// thread t: col-group q=t&(CG-1) (8 cols, uint2 load), edge-group g=t/CG.
// MUST be launched with 128 threads (edge tile == 128).

template <int DO, bool RELU_RES>
__global__ __launch_bounds__(128) void gather_kernel(const unsigned char* __restrict__ hXW,
                                                     float* __restrict__ resOut,
                                                     unsigned short* __restrict__ resBf,
                                                     const int* __restrict__ rowstart,
                                                     const int* __restrict__ esrc,
                                                     const float* __restrict__ dinv,
                                                     const float* __restrict__ bias,
                                                     const float* __restrict__ g,
                                                     const float* __restrict__ be,
                                                     const float* __restrict__ m,
                                                     const float* __restrict__ v) {
    constexpr int CG = DO / 8;    // 16 (DO=128) or 8 (DO=64) col-groups
    constexpr int NG = 128 / CG;  // 8 or 16 edge groups
    constexpr int QN = DO / 4;    // output col-quads
    __shared__ int s_idx[128];
    __shared__ float s_dv[128];
    __shared__ float4 s_red[128][2];
    const int n = blockIdx.x;
    const int t = threadIdx.x;
    const int rs = rowstart[n];
    const int re = rowstart[n + 1];
    const float dn = dinv[n];
    const int q = t & (CG - 1);
    const int grp = t / CG;
    float4 a0l = {0.f, 0.f, 0.f, 0.f}, a0h = {0.f, 0.f, 0.f, 0.f};
    float4 a1l = {0.f, 0.f, 0.f, 0.f}, a1h = {0.f, 0.f, 0.f, 0.f};
    for (int base = rs; base < re; base += 128) {
        const int c = min(128, re - base);
        __syncthreads();
        if (t < c) {
            int s = esrc[base + t];
            s_idx[t] = s;
            s_dv[t] = dinv[s];
        }
        __syncthreads();
        for (int j = grp; j < c; j += 2 * NG) {
            {
                const uint2 u = *(const uint2*)(hXW + (size_t)s_idx[j] * DO + q * 8);
                const float w = s_dv[j];
                const float2v l0 = __builtin_amdgcn_cvt_pk_f32_fp8(u.x, false);
                const float2v h0 = __builtin_amdgcn_cvt_pk_f32_fp8(u.x, true);
                const float2v l1 = __builtin_amdgcn_cvt_pk_f32_fp8(u.y, false);
                const float2v h1 = __builtin_amdgcn_cvt_pk_f32_fp8(u.y, true);
                a0l.x += l0.x * w; a0l.y += l0.y * w; a0l.z += h0.x * w; a0l.w += h0.y * w;
                a0h.x += l1.x * w; a0h.y += l1.y * w; a0h.z += h1.x * w; a0h.w += h1.y * w;
            }
            if (j + NG < c) {
                const uint2 u = *(const uint2*)(hXW + (size_t)s_idx[j + NG] * DO + q * 8);
                const float w = s_dv[j + NG];
                const float2v l0 = __builtin_amdgcn_cvt_pk_f32_fp8(u.x, false);
                const float2v h0 = __builtin_amdgcn_cvt_pk_f32_fp8(u.x, true);
                const float2v l1 = __builtin_amdgcn_cvt_pk_f32_fp8(u.y, false);
                const float2v h1 = __builtin_amdgcn_cvt_pk_f32_fp8(u.y, true);
                a1l.x += l0.x * w; a1l.y += l0.y * w; a1l.z += h0.x * w; a1l.w += h0.y * w;
                a1h.x += l1.x * w; a1h.y += l1.y * w; a1h.z += h1.x * w; a1h.w += h1.y * w;
            }
        }
    }
    a0l.x += a1l.x; a0l.y += a1l.y; a0l.z += a1l.z; a0l.w += a1l.w;
    a0h.x += a1h.x; a0h.y += a1h.y; a0h.z += a1h.z; a0h.w += a1h.w;
    s_red[t][0] = a0l;
    s_red[t][1] = a0h;
    __syncthreads();
    if (t < QN) {
        const int qq = t >> 1, h = t & 1;
        float4 sum = s_red[qq][h];
#pragma unroll
        for (int k = 1; k < NG; ++k) {
            const float4 a = s_red[k * CG + qq][h];
            sum.x += a.x; sum.y += a.y; sum.z += a.z; sum.w += a.w;
        }
        const unsigned su = *(const unsigned*)(hXW + (size_t)n * DO + t * 4);
        const float2v slo = __builtin_amdgcn_cvt_pk_f32_fp8(su, false);
        const float2v shi = __builtin_amdgcn_cvt_pk_f32_fp8(su, true);
        const float4 b4 = *(const float4*)(bias + t * 4);
        const float4 g4 = *(const float4*)(g + t * 4);
        const float4 be4 = *(const float4*)(be + t * 4);
        const float4 m4 = *(const float4*)(m + t * 4);
        const float4 v4 = *(const float4*)(v + t * 4);
        float4 val;
        val.x = (sum.x + dn * slo.x) * dn + b4.x;
        val.y = (sum.y + dn * slo.y) * dn + b4.y;
        val.z = (sum.z + dn * shi.x) * dn + b4.z;
        val.w = (sum.w + dn * shi.y) * dn + b4.w;
        val.x = (val.x - m4.x) * (g4.x * rsqrtf(v4.x + EPS)) + be4.x;
        val.y = (val.y - m4.y) * (g4.y * rsqrtf(v4.y + EPS)) + be4.y;
        val.z = (val.z - m4.z) * (g4.z * rsqrtf(v4.z + EPS)) + be4.z;
        val.w = (val.w - m4.w) * (g4.w * rsqrtf(v4.w + EPS)) + be4.w;
        float4* outp = (float4*)(resOut + (size_t)n * DO + t * 4);
        if (RELU_RES) {
            const float4 r = *outp;
            val.x = fmaxf(val.x, 0.f) + r.x;
            val.y = fmaxf(val.y, 0.f) + r.y;
            val.z = fmaxf(val.z, 0.f) + r.z;
            val.w = fmaxf(val.w, 0.f) + r.w;
            ushort4 bf;
            bf.x = f2bf(val.x); bf.y = f2bf(val.y);
            bf.z = f2bf(val.z); bf.w = f2bf(val.w);
            *(ushort4*)(resBf + (size_t)n * DO + t * 4) = bf;
        }
        *outp = val;
    }
}

// ---------------- launch ----------------

extern "C" void kernel_launch(void* const* d_in, const int* in_sizes, int n_in,
                              void* d_out, int out_size, void* d_ws, size_t ws_size,
                              hipStream_t stream) {
    const float* x    = (const float*)d_in[0];
    const int*   ei   = (const int*)d_in[1];
    const float* W_in = (const float*)d_in[2];
    const float* b_in = (const float*)d_in[3];
    const float* Wl[3] = {(const float*)d_in[4], (const float*)d_in[10], (const float*)d_in[16]};
    const float* bl[3] = {(const float*)d_in[5], (const float*)d_in[11], (const float*)d_in[17]};
    const float* gl[3] = {(const float*)d_in[6], (const float*)d_in[12], (const float*)d_in[18]};
    const float* bel[3] = {(const float*)d_in[7], (const float*)d_in[13], (const float*)d_in[19]};
    const float* ml[3] = {(const float*)d_in[8], (const float*)d_in[14], (const float*)d_in[20]};
    const float* vl[3] = {(const float*)d_in[9], (const float*)d_in[15], (const float*)d_in[21]};
    float* out = (float*)d_out;

    char* ws = (char*)d_ws;
    size_t off = 0;
    auto carve = [&](size_t bytes) {
        void* p = ws + off;
        off += (bytes + 255) & ~(size_t)255;
        return p;
    };
    int*   bcnt     = (int*)carve(NB * sizeof(int));
    int*   bstart   = (int*)carve((NB + 1) * sizeof(int));
    int*   blk_off  = (int*)carve((size_t)NBLK * NB * sizeof(int));
    int*   rowstart = (int*)carve((NN + 1) * sizeof(int));
    float* dinv     = (float*)carve(NN * sizeof(float));
    int*   esrc     = (int*)carve((size_t)NE * sizeof(int));
    float* hA       = (float*)carve((size_t)NN * HD * sizeof(float));
    unsigned short* hAbf = (unsigned short*)carve((size_t)NN * HD * sizeof(unsigned short));
    unsigned char* hB = (unsigned char*)carve((size_t)NN * HD);
    int*   ebin     = (int*)carve((size_t)NE * sizeof(int));
    unsigned short* wf0 = (unsigned short*)carve((size_t)HD * HD * sizeof(unsigned short));
    unsigned short* wf1 = (unsigned short*)carve((size_t)HD * HD * sizeof(unsigned short));
    unsigned short* wf2 = (unsigned short*)carve((size_t)HD * DD * sizeof(unsigned short));
    (void)ws_size;

    hipMemsetAsync(bcnt, 0, NB * sizeof(int), stream);

    wprep<128><<<32, 64, 0, stream>>>(Wl[0], wf0);
    wprep<128><<<32, 64, 0, stream>>>(Wl[1], wf1);
    wprep<64><<<16, 64, 0, stream>>>(Wl[2], wf2);

    p1_bucket_hist<<<NBLK, 256, 0, stream>>>(ei, bcnt, blk_off);
    p2_bucket_scan<<<1, 256, 0, stream>>>(bcnt, bstart);
    p3_bin<<<NBLK, 256, 0, stream>>>(ei, bstart, blk_off, ebin);
    p4_finalize<<<NB, 512, 0, stream>>>(bstart, ebin, esrc, rowstart, dinv);

    inproj_kernel<<<NN / 2, 256, 0, stream>>>(x, W_in, b_in, hA, hAbf);

    // layer 0
    gemm_mfma<128><<<NN / 32, 256, 0, stream>>>(hAbf, wf0, hB);
    gather_kernel<128, true><<<NN, 128, 0, stream>>>(hB, hA, hAbf, rowstart, esrc, dinv,
                                                     bl[0], gl[0], bel[0], ml[0], vl[0]);
    // layer 1
    gemm_mfma<128><<<NN / 32, 256, 0, stream>>>(hAbf, wf1, hB);
    gather_kernel<128, true><<<NN, 128, 0, stream>>>(hB, hA, hAbf, rowstart, esrc, dinv,
                                                     bl[1], gl[1], bel[1], ml[1], vl[1]);
    // layer 2 (BN only, write d_out); 128 threads (edge tile = 128)
    gemm_mfma<64><<<NN / 32, 256, 0, stream>>>(hAbf, wf2, hB);
    gather_kernel<64, false><<<NN, 128, 0, stream>>>(hB, out, (unsigned short*)nullptr,
                                                     rowstart, esrc, dinv,
                                                     bl[2], gl[2], bel[2], ml[2], vl[2]);
}